// Round 1
// baseline (52.469 us; speedup 1.0000x reference)
//
#include <hip/hip_runtime.h>

// TemporalShift: x (256, 12, 196, 64) fp32.
// out[t,h,d,ci] = x[t+1,h,d,ci] if ch<96 && t%8<7
//               = x[t-1,h,d,ci] if 96<=ch<192 && t%8>0
//               = x[t,h,d,ci]   if ch>=192
//               = 0 otherwise
// where ch = h*64+ci, fold boundaries at 96/192 (h==1 splits at ci==32,
// which is float4-aligned -> uniform shift per float4).

#define FRAME_FLOATS 150528   // 12*196*64
#define FRAME_F4     37632    // FRAME_FLOATS/4
#define HEAD_FLOATS  12544    // 196*64

__global__ __launch_bounds__(256) void temporal_shift_kernel(
    const float* __restrict__ x, float* __restrict__ out) {
    const int e4 = blockIdx.x * blockDim.x + threadIdx.x;  // 0..FRAME_F4-1
    const int t  = blockIdx.y;                             // 0..255
    const int e  = e4 * 4;                                 // float offset in frame
    const int h  = e / HEAD_FLOATS;                        // head index 0..11
    const int ci = e & 63;                                 // inner c index

    // channel ch = h*64 + ci ; fold = 96
    int shift;
    if (h == 0 || (h == 1 && ci < 32)) {
        shift = 1;     // left: take next time step
    } else if (h == 1 || h == 2) {
        shift = -1;    // right: take previous time step
    } else {
        shift = 0;     // rest: copy
    }

    const int s = t & 7;  // position within segment of 8
    const bool valid = (shift == 1) ? (s < 7) : ((shift == -1) ? (s > 0) : true);

    float4 v = make_float4(0.f, 0.f, 0.f, 0.f);
    if (valid) {
        const long long src = (long long)(t + shift) * FRAME_FLOATS + e;
        v = *reinterpret_cast<const float4*>(x + src);
    }
    *reinterpret_cast<float4*>(out + (long long)t * FRAME_FLOATS + e) = v;
}

extern "C" void kernel_launch(void* const* d_in, const int* in_sizes, int n_in,
                              void* d_out, int out_size, void* d_ws, size_t ws_size,
                              hipStream_t stream) {
    const float* x = (const float*)d_in[0];
    float* out = (float*)d_out;
    // grid.x covers one frame in float4s: 37632/256 = 147 blocks; grid.y = t
    dim3 grid(FRAME_F4 / 256, 256);
    dim3 block(256);
    temporal_shift_kernel<<<grid, block, 0, stream>>>(x, out);
}

// Round 3
// 50.900 us; speedup vs baseline: 1.0308x; 1.0308x over previous
//
#include <hip/hip_runtime.h>

// TemporalShift: x (256, 12, 196, 64) fp32.
// out[t,h,d,ci] = x[t+1,h,d,ci] if ch<96 && t%8<7
//               = x[t-1,h,d,ci] if 96<=ch<192 && t%8>0
//               = x[t,h,d,ci]   if ch>=192
//               = 0 otherwise
// where ch = h*64+ci, fold boundaries at 96/192 (h==1 splits at ci==32,
// which is float4-aligned -> uniform shift per float4).
//
// Pure streaming op (zero reuse) -> non-temporal loads/stores.
// NOTE: __builtin_nontemporal_* requires a NATIVE vector type, not HIP's
// HIP_vector_type struct -> use clang ext_vector_type.

typedef float f32x4 __attribute__((ext_vector_type(4)));

#define FRAME_FLOATS 150528   // 12*196*64
#define FRAME_F4     37632    // FRAME_FLOATS/4
#define HEAD_FLOATS  12544    // 196*64

__global__ __launch_bounds__(256) void temporal_shift_kernel(
    const float* __restrict__ x, float* __restrict__ out) {
    const int e4 = blockIdx.x * blockDim.x + threadIdx.x;  // 0..FRAME_F4-1
    const int t  = blockIdx.y;                             // 0..255
    const int e  = e4 * 4;                                 // float offset in frame
    const int h  = e / HEAD_FLOATS;                        // head index 0..11
    const int ci = e & 63;                                 // inner c index

    // channel ch = h*64 + ci ; fold = 96
    int shift;
    if (h == 0 || (h == 1 && ci < 32)) {
        shift = 1;     // left: take next time step
    } else if (h == 1 || h == 2) {
        shift = -1;    // right: take previous time step
    } else {
        shift = 0;     // rest: copy
    }

    const int s = t & 7;  // position within segment of 8
    const bool valid = (shift == 1) ? (s < 7) : ((shift == -1) ? (s > 0) : true);

    f32x4 v = (f32x4)(0.f);
    if (valid) {
        const long long src = (long long)(t + shift) * FRAME_FLOATS + e;
        v = __builtin_nontemporal_load(reinterpret_cast<const f32x4*>(x + src));
    }
    __builtin_nontemporal_store(v, reinterpret_cast<f32x4*>(out + (long long)t * FRAME_FLOATS + e));
}

extern "C" void kernel_launch(void* const* d_in, const int* in_sizes, int n_in,
                              void* d_out, int out_size, void* d_ws, size_t ws_size,
                              hipStream_t stream) {
    const float* x = (const float*)d_in[0];
    float* out = (float*)d_out;
    // grid.x covers one frame in float4s: 37632/256 = 147 blocks; grid.y = t
    dim3 grid(FRAME_F4 / 256, 256);
    dim3 block(256);
    temporal_shift_kernel<<<grid, block, 0, stream>>>(x, out);
}